// Round 7
// baseline (309.460 us; speedup 1.0000x reference)
//
#include <hip/hip_runtime.h>
#include <hip/hip_cooperative_groups.h>
#include <math.h>

namespace cg = cooperative_groups;

#define N 2000
#define B 64
#define EMBED 512
#define LABELS 20
#define NM 23   // moments S_0..S_22 per batch
#define NK 22   // exp-series terms

#define GF_KS 8
#define GF_KC 256   // 8*256 = 2048 >= 2000 (zero-padded)
#define FC_KS 32
#define FC_KC 64    // 32*64 = 2048 >= 2000

// ws offsets (floats)
#define SC_OFF 0
#define S_OFF 64
#define FT_OFF 2048
#define MIX_OFF (FT_OFF + N * B)
#define HID_OFF (MIX_OFF + N * B)
#define PGF_OFF (HID_OFF + EMBED * B)      // Pgf[GF_KS][N][64]  (4.1 MB)
#define PFC_OFF (PGF_OFF + GF_KS * N * B)  // Pfc[FC_KS][EMBED][64] (4.2 MB)

__constant__ float c_invfact[NK] = {
    1.0f, 1.0f, 0.5f,
    1.6666666666666666e-01f, 4.1666666666666664e-02f, 8.3333333333333332e-03f,
    1.3888888888888889e-03f, 1.9841269841269841e-04f, 2.4801587301587302e-05f,
    2.7557319223985893e-06f, 2.7557319223985894e-07f, 2.5052108385441720e-08f,
    2.0876756987868100e-09f, 1.6059043836821616e-10f, 1.1470745597729726e-11f,
    7.6471637318198170e-13f, 4.7794773323873860e-14f, 2.8114572543455206e-15f,
    1.5619206968586225e-16f, 8.2206352466243300e-18f, 4.1103176233121650e-19f,
    1.9572941063391263e-20f,
};

union SmemU {
    float xsT[64 * GF_KC];              // 64 KB exactly (P1/P3 X tile)
    struct {
        float tile[64][65];             // P0 transpose
        double sred[8][NM];             // P0 moments cross-wave
    } p0;
    float part[8][64];                  // P5 reduce
};

// One split-K GEMM item: P[ks][row][b] = sum_{k in chunk} A[row][k] * X[k][b]
// X staged into LDS, XOR-swizzled float4 index so stride-KC rows spread banks.
// A loads are wave-uniform (w readfirstlane'd) -> scalar-cache path.
template <int KC>
__device__ __forceinline__ void gemm_item(const float* __restrict__ A, int M,
                                          const float* __restrict__ X,
                                          float* __restrict__ P,
                                          int nt, int ks, float* xsT, int tid) {
    const int XORM = KC / 4 - 1;
    int lane = tid & 63;
    int w = __builtin_amdgcn_readfirstlane(tid >> 6);
    int k0 = ks * KC;
    // stage X chunk: element (b, kk) -> dword b*KC + 4*((kk>>2)^(b&XORM)) + (kk&3)
    for (int i = tid; i < 64 * KC; i += 512) {
        int kk = i >> 6, b = i & 63;
        float v = (k0 + kk < N) ? X[(size_t)(k0 + kk) * 64 + b] : 0.f;
        xsT[b * KC + 4 * ((kk >> 2) ^ (b & XORM)) + (kk & 3)] = v;
    }
    __syncthreads();
    int row0 = nt * 64 + w * 8;
    int rowc[8];
#pragma unroll
    for (int r = 0; r < 8; ++r) rowc[r] = (row0 + r < M) ? (row0 + r) : (M - 1);
    float acc[8];
#pragma unroll
    for (int r = 0; r < 8; ++r) acc[r] = 0.f;
    int lx = lane & XORM;
    const float* xrow = xsT + lane * KC;
#pragma unroll 2
    for (int k4 = 0; k4 < KC / 4; ++k4) {
        int kb = k0 + 4 * k4;
        int kbc = (kb + 3 < N) ? kb : (N - 4);   // padded k's have x==0
        float4 xv = *(const float4*)(xrow + 4 * (k4 ^ lx));
#pragma unroll
        for (int r = 0; r < 8; ++r) {
            float4 g = *(const float4*)(A + (size_t)rowc[r] * N + kbc);
            acc[r] = fmaf(g.x, xv.x, acc[r]);
            acc[r] = fmaf(g.y, xv.y, acc[r]);
            acc[r] = fmaf(g.z, xv.z, acc[r]);
            acc[r] = fmaf(g.w, xv.w, acc[r]);
        }
    }
#pragma unroll
    for (int r = 0; r < 8; ++r) {
        int row = row0 + r;
        if (row < M) P[((size_t)ks * M + row) * 64 + lane] = acc[r];
    }
    __syncthreads();
}

__global__ __launch_bounds__(512) void mega_kernel(
        const float* __restrict__ f, const float* __restrict__ G,
        const float* __restrict__ tw, const float* __restrict__ tb,
        const float* __restrict__ pw,
        const float* __restrict__ w1, const float* __restrict__ b1,
        const float* __restrict__ w2, const float* __restrict__ b2,
        float* __restrict__ out, float* __restrict__ ws) {
    __shared__ SmemU sm;
    cg::grid_group grid = cg::this_grid();
    int bid = blockIdx.x;
    int tid = threadIdx.x;
    int lane = tid & 63, w = tid >> 6;

    float* sc = ws + SC_OFF;
    float* S = ws + S_OFF;
    float* fT = ws + FT_OFF;
    float* mixT = ws + MIX_OFF;
    float* hidden = ws + HID_OFF;
    float* Pgf = ws + PGF_OFF;
    float* Pfc = ws + PFC_OFF;

    // ---------- P0: transpose f -> fT | per-batch moments | A,C2 ----------
    if (bid < 32) {
        int m0 = bid * 64;
        for (int bb = w; bb < 64; bb += 8)
            sm.p0.tile[lane][bb] = (m0 + lane < N) ? f[(size_t)bb * N + m0 + lane] : 0.f;
        __syncthreads();
        for (int mm = w; mm < 64; mm += 8)
            if (m0 + mm < N) fT[(size_t)(m0 + mm) * 64 + lane] = sm.p0.tile[mm][lane];
    } else if (bid < 96) {
        int b = bid - 32;
        const float* fb = f + (size_t)b * N;
        double acc[NM];
#pragma unroll
        for (int k = 0; k < NM; ++k) acc[k] = 0.0;
        for (int m = tid; m < N; m += 512) {
            double x = (double)fb[m];
            double p = 1.0;
#pragma unroll
            for (int k = 0; k < NM; ++k) { acc[k] += p; p *= x; }
        }
        for (int off = 32; off; off >>= 1) {
#pragma unroll
            for (int k = 0; k < NM; ++k) acc[k] += __shfl_down(acc[k], off);
        }
        if (lane == 0) {
#pragma unroll
            for (int k = 0; k < NM; ++k) sm.p0.sred[w][k] = acc[k];
        }
        __syncthreads();
        if (tid < NM) {
            double s = 0.0;
#pragma unroll
            for (int ww = 0; ww < 8; ++ww) s += sm.p0.sred[ww][tid];
            S[tid * 64 + b] = (float)s;
        }
    } else if (bid == 96) {
        if (tid < 64) {
            float a = tw[tid] * pw[tid];
            float c = tb[tid] * pw[tid];
            for (int off = 32; off; off >>= 1) {
                a += __shfl_down(a, off);
                c += __shfl_down(c, off);
            }
            if (tid == 0) { sc[0] = a; sc[1] = c; }
        }
    }
    grid.sync();

    // ---------- P1: gf GEMM (32 nt x 8 ks = 256 items, one per block) ----------
    gemm_item<GF_KC>(G, N, fT, Pgf, bid >> 3, bid & 7, sm.xsT, tid);
    grid.sync();

    // ---------- P2: reduce partials + poly-softmax + relu + residual ----------
    {
        int flat = bid * 512 + tid;
        if (flat < N * 64) {
            int b = flat & 63;
            float s = 0.f;
#pragma unroll
            for (int k = 0; k < GF_KS; ++k) s += Pgf[(size_t)k * N * 64 + flat];
            float fn = fT[flat];
            float Ax = sc[0], C2 = sc[1];
            float t = fmaf(Ax, fn, C2);
            float Z = 0.f, Wv = 0.f, tp = 1.f;
#pragma unroll
            for (int k = 0; k < NK; ++k) {
                float c = tp * c_invfact[k];
                Z = fmaf(c, S[k * 64 + b], Z);
                Wv = fmaf(c, S[(k + 1) * 64 + b], Wv);
                tp *= t;
            }
            float r = fmaxf(s + Wv / Z, 0.f);
            mixT[flat] = r + fn;
        }
    }
    grid.sync();

    // ---------- P3: fc1 GEMM (8 nt x 32 ks = 256 items) ----------
    gemm_item<FC_KC>(w1, EMBED, mixT, Pfc, bid >> 5, bid & 31, sm.xsT, tid);
    grid.sync();

    // ---------- P4: reduce fc1 partials + bias + tanh ----------
    {
        int flat = bid * 512 + tid;
        if (flat < EMBED * 64) {
            int e = flat >> 6;
            float s = 0.f;
#pragma unroll
            for (int k = 0; k < FC_KS; ++k) s += Pfc[(size_t)k * EMBED * 64 + flat];
            hidden[flat] = tanhf(s + b1[e]);
        }
    }
    grid.sync();

    // ---------- P5: fc2 logits ----------
    if (bid < LABELS) {
        int l = bid;
        const float* h = hidden + (size_t)(w * 64) * 64 + lane;
        const float* wr = w2 + (size_t)l * EMBED + w * 64;
        float a0 = 0.f, a1 = 0.f;
#pragma unroll
        for (int i = 0; i < 64; i += 2) {
            a0 = fmaf(wr[i], h[(size_t)i * 64], a0);
            a1 = fmaf(wr[i + 1], h[(size_t)(i + 1) * 64], a1);
        }
        sm.part[w][lane] = a0 + a1;
        __syncthreads();
        if (w == 0) {
            float s = 0.f;
#pragma unroll
            for (int ww = 0; ww < 8; ++ww) s += sm.part[ww][lane];
            out[(size_t)lane * LABELS + l] = s + b2[l];
        }
    }
}

extern "C" void kernel_launch(void* const* d_in, const int* in_sizes, int n_in,
                              void* d_out, int out_size, void* d_ws, size_t ws_size,
                              hipStream_t stream) {
    const float* f = (const float*)d_in[0];
    const float* G = (const float*)d_in[1];
    const float* tw = (const float*)d_in[2];
    const float* tb = (const float*)d_in[3];
    const float* pw = (const float*)d_in[4];
    const float* w1 = (const float*)d_in[6];
    const float* b1 = (const float*)d_in[7];
    const float* w2 = (const float*)d_in[8];
    const float* b2 = (const float*)d_in[9];
    float* out = (float*)d_out;
    float* wsp = (float*)d_ws;

    void* args[] = {(void*)&f, (void*)&G, (void*)&tw, (void*)&tb, (void*)&pw,
                    (void*)&w1, (void*)&b1, (void*)&w2, (void*)&b2,
                    (void*)&out, (void*)&wsp};
    hipLaunchCooperativeKernel(mega_kernel, dim3(256), dim3(512), args, 0u, stream);
}

// Round 8
// 122.992 us; speedup vs baseline: 2.5161x; 2.5161x over previous
//
#include <hip/hip_runtime.h>
#include <math.h>

#define B 64
#define N 2000
#define R 64
#define EMBED 512
#define LABELS 20

#define NM 23   // moments S_0..S_22 per batch
#define NK 22   // exp-series terms

#define KS 25   // k-splits
#define KC 80   // k-chunk (25*80 = 2000 exactly)

// ws layout (floats):
#define SC_OFF 0                         // A, C2
#define S_OFF 64                         // S[NM][64]
#define FT_OFF 2048                      // fT[N][64]
#define MIX_OFF (FT_OFF + N * B)         // mixT[N][64]
#define HID_OFF (MIX_OFF + N * B)        // hidden[EMBED][64]
#define PGF_OFF (HID_OFF + EMBED * B)    // Pgf[KS][N][64]    (12.8 MB)
#define PFC_OFF (PGF_OFF + KS * N * B)   // Pfc[KS][EMBED][64] (3.3 MB)

__constant__ float c_invfact[NK] = {
    1.0f, 1.0f, 0.5f,
    1.6666666666666666e-01f, 4.1666666666666664e-02f, 8.3333333333333332e-03f,
    1.3888888888888889e-03f, 1.9841269841269841e-04f, 2.4801587301587302e-05f,
    2.7557319223985893e-06f, 2.7557319223985894e-07f, 2.5052108385441720e-08f,
    2.0876756987868100e-09f, 1.6059043836821616e-10f, 1.1470745597729726e-11f,
    7.6471637318198170e-13f, 4.7794773323873860e-14f, 2.8114572543455206e-15f,
    1.5619206968586225e-16f, 8.2206352466243300e-18f, 4.1103176233121650e-19f,
    1.9572941063391263e-20f,
};

// ---------------- kernel 1 (fused): moments | scalars | transpose ----------------
// bid 0..63: per-batch power sums (f64). bid 64: A, C2. bid 65..96: fT tiles.
__global__ __launch_bounds__(256) void prep_fused(const float* __restrict__ f,
                                                  const float* __restrict__ tw,
                                                  const float* __restrict__ tb,
                                                  const float* __restrict__ pw,
                                                  float* __restrict__ sc,
                                                  float* __restrict__ S,
                                                  float* __restrict__ fT) {
    __shared__ float tile[64][65];
    __shared__ double sred[4][NM];
    int bid = blockIdx.x;
    int tid = threadIdx.x;
    if (bid >= 65) {
        int m0 = (bid - 65) * 64;
        int lane = tid & 63, w = tid >> 6;
        for (int bb = w; bb < 64; bb += 4)
            tile[lane][bb] = (m0 + lane < N) ? f[(size_t)bb * N + m0 + lane] : 0.f;
        __syncthreads();
        for (int mm = w; mm < 64; mm += 4)
            if (m0 + mm < N) fT[(size_t)(m0 + mm) * 64 + lane] = tile[mm][lane];
        return;
    }
    if (bid == 64) {
        if (tid < R) {
            float a = tw[tid] * pw[tid];
            float c = tb[tid] * pw[tid];
            for (int off = 32; off; off >>= 1) {
                a += __shfl_down(a, off);
                c += __shfl_down(c, off);
            }
            if (tid == 0) { sc[0] = a; sc[1] = c; }
        }
        return;
    }
    const float* fb = f + (size_t)bid * N;
    double acc[NM];
#pragma unroll
    for (int k = 0; k < NM; ++k) acc[k] = 0.0;
    for (int m = tid; m < N; m += 256) {
        double x = (double)fb[m];
        double p = 1.0;
#pragma unroll
        for (int k = 0; k < NM; ++k) { acc[k] += p; p *= x; }
    }
    for (int off = 32; off; off >>= 1) {
#pragma unroll
        for (int k = 0; k < NM; ++k) acc[k] += __shfl_down(acc[k], off);
    }
    int w = tid >> 6, lane = tid & 63;
    if (lane == 0) {
#pragma unroll
        for (int k = 0; k < NM; ++k) sred[w][k] = acc[k];
    }
    __syncthreads();
    if (tid < NM) {
        double s = sred[0][tid] + sred[1][tid] + sred[2][tid] + sred[3][tid];
        S[tid * 64 + bid] = (float)s;
    }
}

// ---------------- scalar-operand split-K GEMM (256 thr = 4 waves, 8 rows/wave) ----
// P[ks][row][b] = sum_{k in chunk ks} A[row][k] * X[k][b]
// A row-major [M][N]; X k-major [N][64]. A values wave-uniform (w readfirstlane'd),
// X slice lives in VGPRs (vf[80], coalesced loads). No LDS, no barriers.
// 256-thr blocks: VGPR ~140 -> 3 blocks/CU = 12 waves/CU for latency hiding.
template <int M>
__global__ __launch_bounds__(256) void gemm_part(const float* __restrict__ A,
                                                 const float* __restrict__ X,
                                                 float* __restrict__ P) {
    int tid = threadIdx.x;
    int lane = tid & 63;
    int w = __builtin_amdgcn_readfirstlane(tid >> 6);   // 0..3
    int ks = blockIdx.x % KS;
    int nt = blockIdx.x / KS;
    int k0 = ks * KC;
    int row0 = nt * 32 + w * 8;

    float vf[KC];
#pragma unroll
    for (int j = 0; j < KC; ++j) vf[j] = X[(size_t)(k0 + j) * 64 + lane];

    int rowc[8];
#pragma unroll
    for (int r = 0; r < 8; ++r) rowc[r] = (row0 + r < M) ? (row0 + r) : (M - 1);

    float acc[8];
#pragma unroll
    for (int r = 0; r < 8; ++r) acc[r] = 0.f;

#pragma unroll
    for (int j4 = 0; j4 < KC / 4; ++j4) {
        float4 g[8];
#pragma unroll
        for (int r = 0; r < 8; ++r)
            g[r] = *(const float4*)(A + (size_t)rowc[r] * N + k0 + 4 * j4);
#pragma unroll
        for (int r = 0; r < 8; ++r) {
            acc[r] = fmaf(g[r].x, vf[4 * j4 + 0], acc[r]);
            acc[r] = fmaf(g[r].y, vf[4 * j4 + 1], acc[r]);
            acc[r] = fmaf(g[r].z, vf[4 * j4 + 2], acc[r]);
            acc[r] = fmaf(g[r].w, vf[4 * j4 + 3], acc[r]);
        }
    }
#pragma unroll
    for (int r = 0; r < 8; ++r) {
        int row = row0 + r;
        if (row < M) P[((size_t)ks * M + row) * 64 + lane] = acc[r];
    }
}

// ---------------- reduce gf partials + softmax-poly + relu + residual ----------------
__global__ __launch_bounds__(256) void reduce_gf(const float* __restrict__ P,
                                                 const float* __restrict__ fT,
                                                 const float* __restrict__ sc,
                                                 const float* __restrict__ S,
                                                 float* __restrict__ mixT) {
    int flat = blockIdx.x * 256 + threadIdx.x;   // 0..127999
    int b = flat & 63;
    float s = 0.f;
#pragma unroll
    for (int k = 0; k < KS; ++k) s += P[(size_t)k * N * 64 + flat];
    float fn = fT[flat];                         // fT[n][b], flat = n*64+b
    float A = sc[0], C2 = sc[1];
    float t = fmaf(A, fn, C2);
    float Z = 0.f, Wv = 0.f, tp = 1.f;
#pragma unroll
    for (int k = 0; k < NK; ++k) {
        float c = tp * c_invfact[k];
        Z = fmaf(c, S[k * 64 + b], Z);
        Wv = fmaf(c, S[(k + 1) * 64 + b], Wv);
        tp *= t;
    }
    float r = fmaxf(s + Wv / Z, 0.f);
    mixT[flat] = r + fn;
}

// ---------------- reduce fc1 partials + bias + tanh ----------------
__global__ __launch_bounds__(256) void reduce_fc1(const float* __restrict__ P,
                                                  const float* __restrict__ b1,
                                                  float* __restrict__ hidden) {
    int flat = blockIdx.x * 256 + threadIdx.x;   // 0..32767
    int e = flat >> 6;
    float s = 0.f;
#pragma unroll
    for (int k = 0; k < KS; ++k) s += P[(size_t)k * EMBED * 64 + flat];
    hidden[flat] = tanhf(s + b1[e]);
}

// ---------------- logits ----------------
__global__ __launch_bounds__(256) void fc2_kernel(const float* __restrict__ hidden,
                                                  const float* __restrict__ w2,
                                                  const float* __restrict__ b2,
                                                  float* __restrict__ out) {
    int l = blockIdx.x;
    int tid = threadIdx.x;
    int lane = tid & 63;
    int w = tid >> 6;
    const float4* W = (const float4*)(w2 + (size_t)l * EMBED) + w * 32;
    const float* h = hidden + (size_t)(w * 128) * B + lane;
    float a0 = 0.f, a1 = 0.f, a2 = 0.f, a3 = 0.f;
#pragma unroll 4
    for (int i = 0; i < 32; ++i) {
        float4 g = W[i];
        a0 = fmaf(g.x, h[(4 * i + 0) * B], a0);
        a1 = fmaf(g.y, h[(4 * i + 1) * B], a1);
        a2 = fmaf(g.z, h[(4 * i + 2) * B], a2);
        a3 = fmaf(g.w, h[(4 * i + 3) * B], a3);
    }
    __shared__ float part[4][64];
    part[w][lane] = (a0 + a1) + (a2 + a3);
    __syncthreads();
    if (w == 0) {
        out[(size_t)lane * LABELS + l] =
            part[0][lane] + part[1][lane] + part[2][lane] + part[3][lane] + b2[l];
    }
}

extern "C" void kernel_launch(void* const* d_in, const int* in_sizes, int n_in,
                              void* d_out, int out_size, void* d_ws, size_t ws_size,
                              hipStream_t stream) {
    const float* feature = (const float*)d_in[0];
    const float* init_graph = (const float*)d_in[1];
    const float* theta_w = (const float*)d_in[2];
    const float* theta_b = (const float*)d_in[3];
    const float* phi_w = (const float*)d_in[4];
    const float* fc1_w = (const float*)d_in[6];
    const float* fc1_b = (const float*)d_in[7];
    const float* fc2_w = (const float*)d_in[8];
    const float* fc2_b = (const float*)d_in[9];
    float* out = (float*)d_out;

    float* ws = (float*)d_ws;
    float* sc = ws + SC_OFF;
    float* S = ws + S_OFF;
    float* fT = ws + FT_OFF;
    float* mixT = ws + MIX_OFF;
    float* hidden = ws + HID_OFF;
    float* Pgf = ws + PGF_OFF;
    float* Pfc = ws + PFC_OFF;

    // moments + scalars + transpose, fused (97 blocks)
    hipLaunchKernelGGL(prep_fused, dim3(65 + (N + 63) / 64), dim3(256), 0, stream,
                       feature, theta_w, theta_b, phi_w, sc, S, fT);
    // gf: G[2000][2000] x fT -> Pgf   (63 row-tiles x 25 k-splits)
    hipLaunchKernelGGL((gemm_part<N>), dim3(63 * KS), dim3(256), 0, stream,
                       init_graph, fT, Pgf);
    hipLaunchKernelGGL(reduce_gf, dim3(N * B / 256), dim3(256), 0, stream,
                       Pgf, fT, sc, S, mixT);
    // fc1: w1[512][2000] x mixT -> Pfc  (16 row-tiles x 25 k-splits)
    hipLaunchKernelGGL((gemm_part<EMBED>), dim3(16 * KS), dim3(256), 0, stream,
                       fc1_w, mixT, Pfc);
    hipLaunchKernelGGL(reduce_fc1, dim3(EMBED * B / 256), dim3(256), 0, stream,
                       Pfc, fc1_b, hidden);
    hipLaunchKernelGGL(fc2_kernel, dim3(LABELS), dim3(256), 0, stream,
                       hidden, fc2_w, fc2_b, out);
}